// Round 2
// baseline (275.617 us; speedup 1.0000x reference)
//
#include <hip/hip_runtime.h>

// HybridQLSTMCell, algebraically collapsed quantum layer.
// gate_vec = [x|hx] @ W.T + b  (4x68 matvec per row)
// z_w = cos(gate_vec_w + theta_w)
// <Z0>=z1*z2*z3, <Z1>=z0*z1, <Z2>=z0*z1*z2, <Z3>=z0*z1*z2*z3
// f,i,o = sigmoid(<Z>), g = tanh(<Z>); cx' = f*cx + i*g; hx' = o*tanh(cx')
//
// This version stages x through LDS to fix the stride-256 global read:
//  - global loads are lane-adjacent float4 (perfect coalescing)
//  - LDS row stride 65 floats: scatter-write and row-read are both exactly
//    2-way bank aliased (free on 32-bank/64-lane CDNA4, m136)
//  - W is transposed to [68][4] in LDS: inner loop does one wave-uniform
//    broadcast ds_read_b128 per k.

#define ROWS 256   // rows (batch elements) per block == blockDim.x
#define XPAD 65    // LDS row stride in floats (64 data + 1 pad)

__device__ __forceinline__ float sigm_fast(float v) {
    return 1.0f / (1.0f + __expf(-v));
}
__device__ __forceinline__ float tanh_fast(float v) {
    // 1 - 2/(e^{2v}+1): correct limits at +/-inf (no inf/inf NaN)
    return 1.0f - 2.0f / (__expf(2.0f * v) + 1.0f);
}

__global__ __launch_bounds__(256) void qlstm_kernel(
    const float* __restrict__ x,    // [B,64]
    const float* __restrict__ hx,   // [B,4]
    const float* __restrict__ cx,   // [B,4]
    const float* __restrict__ W,    // [4,68]
    const float* __restrict__ b,    // [4]
    const float* __restrict__ th_f, const float* __restrict__ th_i,
    const float* __restrict__ th_g, const float* __restrict__ th_o,
    float* __restrict__ out_h,      // [B,4]
    float* __restrict__ out_c,      // [B,4]
    int nB)
{
    __shared__ float sX[ROWS * XPAD];  // 66,560 B
    __shared__ float sWt[68 * 4];      // W transposed: sWt[k*4+g] = W[g][k]
    __shared__ float sP[20];           // b[4], th_f[4], th_i[4], th_g[4], th_o[4]
    const int t = threadIdx.x;

    for (int i = t; i < 272; i += 256) {
        const int g = i / 68, k = i % 68;
        sWt[k * 4 + g] = W[i];
    }
    if (t < 4) {
        sP[t]      = b[t];
        sP[4 + t]  = th_f[t];
        sP[8 + t]  = th_i[t];
        sP[12 + t] = th_g[t];
        sP[16 + t] = th_o[t];
    }

    const int rowBase = blockIdx.x * ROWS;
    const int rowsHere = min(ROWS, nB - rowBase);

    // ---- stage x tile (rowsHere x 64) into LDS, coalesced ----
    const float4* xg = (const float4*)(x + (size_t)rowBase * 64);
#pragma unroll
    for (int j = 0; j < 16; ++j) {
        const int fi = j * 256 + t;        // float4 index within tile
        const int f = fi * 4;              // element index within tile
        const int row = f >> 6;
        if (row < rowsHere) {
            const float4 v = xg[fi];
            float* p = &sX[row * XPAD + (f & 63)];
            p[0] = v.x; p[1] = v.y; p[2] = v.z; p[3] = v.w;
        }
    }
    __syncthreads();

    const int idx = rowBase + t;
    if (t >= rowsHere) return;

    // ---- 4x68 matvec: gate_vec = [x|hx] @ W.T + b ----
    float g0 = sP[0], g1 = sP[1], g2 = sP[2], g3 = sP[3];
    const float* xr = &sX[t * XPAD];
#pragma unroll
    for (int k = 0; k < 64; ++k) {
        const float xv = xr[k];
        const float4 w = *(const float4*)&sWt[k * 4];  // wave-uniform broadcast
        g0 += xv * w.x; g1 += xv * w.y; g2 += xv * w.z; g3 += xv * w.w;
    }
    const float4 h = *(const float4*)(hx + (size_t)idx * 4);
#pragma unroll
    for (int k = 64; k < 68; ++k) {
        const float hv = (k == 64) ? h.x : (k == 65) ? h.y : (k == 66) ? h.z : h.w;
        const float4 w = *(const float4*)&sWt[k * 4];
        g0 += hv * w.x; g1 += hv * w.y; g2 += hv * w.z; g3 += hv * w.w;
    }

    // ---- collapsed quantum expectations per gate ----
    float e[4][4];  // [gate f,i,g,o][wire]
#pragma unroll
    for (int q = 0; q < 4; ++q) {
        const float* th = &sP[4 + 4 * q];
        const float z0 = __cosf(g0 + th[0]);
        const float z1 = __cosf(g1 + th[1]);
        const float z2 = __cosf(g2 + th[2]);
        const float z3 = __cosf(g3 + th[3]);
        const float e1 = z0 * z1;
        const float e2 = e1 * z2;
        e[q][0] = z1 * z2 * z3;
        e[q][1] = e1;
        e[q][2] = e2;
        e[q][3] = e2 * z3;
    }

    const float4 c = *(const float4*)(cx + (size_t)idx * 4);
    float cn[4], hn[4];
#pragma unroll
    for (int w = 0; w < 4; ++w) {
        const float fv = sigm_fast(e[0][w]);
        const float iv = sigm_fast(e[1][w]);
        const float gv = tanh_fast(e[2][w]);
        const float ov = sigm_fast(e[3][w]);
        const float cold = (w == 0) ? c.x : (w == 1) ? c.y : (w == 2) ? c.z : c.w;
        cn[w] = fv * cold + iv * gv;
        hn[w] = ov * tanh_fast(cn[w]);
    }
    *(float4*)(out_c + (size_t)idx * 4) = make_float4(cn[0], cn[1], cn[2], cn[3]);
    *(float4*)(out_h + (size_t)idx * 4) = make_float4(hn[0], hn[1], hn[2], hn[3]);
}

extern "C" void kernel_launch(void* const* d_in, const int* in_sizes, int n_in,
                              void* d_out, int out_size, void* d_ws, size_t ws_size,
                              hipStream_t stream) {
    const float* x    = (const float*)d_in[0];
    const float* hx   = (const float*)d_in[1];
    const float* cx   = (const float*)d_in[2];
    const float* W    = (const float*)d_in[3];
    const float* b    = (const float*)d_in[4];
    const float* th_f = (const float*)d_in[5];
    const float* th_i = (const float*)d_in[6];
    const float* th_g = (const float*)d_in[7];
    const float* th_o = (const float*)d_in[8];

    const int nB = in_sizes[0] / 64;          // 524288
    float* out_h = (float*)d_out;             // [B,4]
    float* out_c = out_h + (size_t)nB * 4;    // [B,4]

    const int blocks = (nB + ROWS - 1) / ROWS;  // 2048
    hipLaunchKernelGGL(qlstm_kernel, dim3(blocks), dim3(256), 0, stream,
                       x, hx, cx, W, b, th_f, th_i, th_g, th_o, out_h, out_c, nB);
}

// Round 3
// 249.728 us; speedup vs baseline: 1.1037x; 1.1037x over previous
//
#include <hip/hip_runtime.h>

// HybridQLSTMCell, algebraically collapsed quantum layer.
//   gate_vec = [x|hx] @ W.T + b                       (4x68 matvec per row)
//   z_w^q = cos(gate_vec_w + theta_q_w)
//   <Z0>=z1z2z3  <Z1>=z0z1  <Z2>=z0z1z2  <Z3>=z0z1z2z3
//   f,i,o = sigmoid(<Z>), g = tanh(<Z>);  cx' = f*cx + i*g;  hx' = o*tanh(cx')
//
// Decomposition: 16 lanes per row. Lane ks (=lane&15) owns k = 4*ks..4*ks+3
// with its 4x4 W sub-block in registers. Per wave-instruction the 64 lanes
// read one contiguous 1 KB block of x (4 rows x 256 B) -> perfect coalescing,
// no LDS staging. Gate sums reduced with a width-16 shfl_xor butterfly.
// Quantum tail: lane ks<4 computes gate ks (4 cos + products + activation),
// 12 shfl gather to the row leader (ks==0) for the LSTM combine + stores.

__device__ __forceinline__ float tanh_fast(float v) {
    // 1 - 2/(e^{2v}+1): correct limits at +/-inf (no inf/inf NaN)
    return 1.0f - 2.0f / (__expf(2.0f * v) + 1.0f);
}

#define ITERS 16   // row-groups per block: 16 iters x 16 rows = 256 rows/block

__global__ __launch_bounds__(256) void qlstm_kernel(
    const float* __restrict__ x,    // [B,64]
    const float* __restrict__ hx,   // [B,4]
    const float* __restrict__ cx,   // [B,4]
    const float* __restrict__ W,    // [4,68]
    const float* __restrict__ b,    // [4]
    const float* __restrict__ th_f, const float* __restrict__ th_i,
    const float* __restrict__ th_g, const float* __restrict__ th_o,
    float* __restrict__ out_h,      // [B,4]
    float* __restrict__ out_c,      // [B,4]
    int nB)
{
    __shared__ float sWt[68 * 4];  // sWt[k*4+g] = W[g][k]
    __shared__ float sP[20];       // b[4], th_f[4], th_i[4], th_g[4], th_o[4]
    const int t = threadIdx.x;
    for (int i = t; i < 272; i += 256) {
        const int g = i / 68, k = i % 68;
        sWt[k * 4 + g] = W[i];
    }
    if (t < 4) {
        sP[t]      = b[t];
        sP[4 + t]  = th_f[t];
        sP[8 + t]  = th_i[t];
        sP[12 + t] = th_g[t];
        sP[16 + t] = th_o[t];
    }
    __syncthreads();

    const int lane = t & 63;
    const int wave = t >> 6;
    const int ks   = lane & 15;    // k-slot within row-group
    const int sub  = lane >> 4;    // row within 4-row group
    const int qq   = ks & 3;       // gate id for the act phase (valid for ks<4)

    // per-lane W slice: Wr[j].{x,y,z,w} = W[gate 0..3][ks*4+j]
    const float4 Wr0 = *(const float4*)&sWt[(ks * 4 + 0) * 4];
    const float4 Wr1 = *(const float4*)&sWt[(ks * 4 + 1) * 4];
    const float4 Wr2 = *(const float4*)&sWt[(ks * 4 + 2) * 4];
    const float4 Wr3 = *(const float4*)&sWt[(ks * 4 + 3) * 4];
    const bool isg = (ks < 4);
    float4 Wh = make_float4(0.f, 0.f, 0.f, 0.f);   // W[q][64+ks] for hx part
    if (isg) Wh = *(const float4*)&sWt[(64 + ks) * 4];
    // unified activation: act(v) = 1 - K/(exp(S*v)+1);  K=S=1 -> sigmoid,
    // K=S=2 -> tanh (gate q==2 is g/tanh)
    const float Kc = (qq == 2) ? 2.0f : 1.0f;
    const float Sc = (qq == 2) ? 2.0f : 1.0f;

    const float4* xg = (const float4*)x;
    const int base = blockIdx.x * (16 * ITERS);

#pragma unroll 4
    for (int i = 0; i < ITERS; ++i) {
        const int row = base + i * 16 + wave * 4 + sub;
        const bool valid = row < nB;

        // ---- coalesced x read: 64 lanes = contiguous 1 KB ----
        float4 xv = make_float4(0.f, 0.f, 0.f, 0.f);
        if (valid) xv = xg[(size_t)row * 16 + ks];

        float g0 = xv.x * Wr0.x + xv.y * Wr1.x + xv.z * Wr2.x + xv.w * Wr3.x;
        float g1 = xv.x * Wr0.y + xv.y * Wr1.y + xv.z * Wr2.y + xv.w * Wr3.y;
        float g2 = xv.x * Wr0.z + xv.y * Wr1.z + xv.z * Wr2.z + xv.w * Wr3.z;
        float g3 = xv.x * Wr0.w + xv.y * Wr1.w + xv.z * Wr2.w + xv.w * Wr3.w;
        if (isg && valid) {
            const float hv = hx[(size_t)row * 4 + ks];
            g0 += hv * Wh.x; g1 += hv * Wh.y; g2 += hv * Wh.z; g3 += hv * Wh.w;
        }

        // ---- width-16 butterfly: all 16 lanes get the full 4 gate sums ----
#pragma unroll
        for (int s = 1; s < 16; s <<= 1) {
            g0 += __shfl_xor(g0, s, 16);
            g1 += __shfl_xor(g1, s, 16);
            g2 += __shfl_xor(g2, s, 16);
            g3 += __shfl_xor(g3, s, 16);
        }
        g0 += sP[0]; g1 += sP[1]; g2 += sP[2]; g3 += sP[3];   // + bias

        // ---- lane qq computes gate qq: cos, prefix products, activation ----
        const float z0 = __cosf(g0 + sP[4 + qq * 4 + 0]);
        const float z1 = __cosf(g1 + sP[4 + qq * 4 + 1]);
        const float z2 = __cosf(g2 + sP[4 + qq * 4 + 2]);
        const float z3 = __cosf(g3 + sP[4 + qq * 4 + 3]);
        const float e1 = z0 * z1, e2 = e1 * z2;
        const float e0 = z1 * z2 * z3, e3 = e2 * z3;
        const float a0 = 1.0f - Kc / (__expf(Sc * e0) + 1.0f);
        const float a1 = 1.0f - Kc / (__expf(Sc * e1) + 1.0f);
        const float a2 = 1.0f - Kc / (__expf(Sc * e2) + 1.0f);
        const float a3 = 1.0f - Kc / (__expf(Sc * e3) + 1.0f);

        // ---- gather i,g,o acts to the row leader (its own a* are f) ----
        const float i0 = __shfl(a0, 1, 16), i1 = __shfl(a1, 1, 16);
        const float i2 = __shfl(a2, 1, 16), i3 = __shfl(a3, 1, 16);
        const float G0 = __shfl(a0, 2, 16), G1 = __shfl(a1, 2, 16);
        const float G2 = __shfl(a2, 2, 16), G3 = __shfl(a3, 2, 16);
        const float o0 = __shfl(a0, 3, 16), o1 = __shfl(a1, 3, 16);
        const float o2 = __shfl(a2, 3, 16), o3 = __shfl(a3, 3, 16);

        if (ks == 0 && valid) {
            const float4 c = *(const float4*)(cx + (size_t)row * 4);
            const float cn0 = a0 * c.x + i0 * G0;
            const float cn1 = a1 * c.y + i1 * G1;
            const float cn2 = a2 * c.z + i2 * G2;
            const float cn3 = a3 * c.w + i3 * G3;
            const float hn0 = o0 * tanh_fast(cn0);
            const float hn1 = o1 * tanh_fast(cn1);
            const float hn2 = o2 * tanh_fast(cn2);
            const float hn3 = o3 * tanh_fast(cn3);
            *(float4*)(out_c + (size_t)row * 4) = make_float4(cn0, cn1, cn2, cn3);
            *(float4*)(out_h + (size_t)row * 4) = make_float4(hn0, hn1, hn2, hn3);
        }
    }
}

extern "C" void kernel_launch(void* const* d_in, const int* in_sizes, int n_in,
                              void* d_out, int out_size, void* d_ws, size_t ws_size,
                              hipStream_t stream) {
    const float* x    = (const float*)d_in[0];
    const float* hx   = (const float*)d_in[1];
    const float* cx   = (const float*)d_in[2];
    const float* W    = (const float*)d_in[3];
    const float* b    = (const float*)d_in[4];
    const float* th_f = (const float*)d_in[5];
    const float* th_i = (const float*)d_in[6];
    const float* th_g = (const float*)d_in[7];
    const float* th_o = (const float*)d_in[8];

    const int nB = in_sizes[0] / 64;          // 524288
    float* out_h = (float*)d_out;             // [B,4]
    float* out_c = out_h + (size_t)nB * 4;    // [B,4]

    const int rowsPerBlock = 16 * ITERS;      // 256
    const int blocks = (nB + rowsPerBlock - 1) / rowsPerBlock;  // 2048
    hipLaunchKernelGGL(qlstm_kernel, dim3(blocks), dim3(256), 0, stream,
                       x, hx, cx, W, b, th_f, th_i, th_g, th_o, out_h, out_c, nB);
}

// Round 4
// 219.372 us; speedup vs baseline: 1.2564x; 1.1384x over previous
//
#include <hip/hip_runtime.h>

// HybridQLSTMCell, algebraically collapsed quantum layer.
//   gate_vec = [x|hx] @ W.T + b                      (4x68 matvec per row)
//   z_w^q = cos(gate_vec_w + theta_q_w)
//   <Z0>=z1z2z3  <Z1>=z0z1  <Z2>=z0z1z2  <Z3>=z0z1z2z3
//   f,i,o = sigmoid(<Z>), g = tanh(<Z>);  cx' = f*cx + i*g;  hx' = o*tanh(cx')
//
// Decomposition: 4 lanes (one quad) per row. Lane q owns interleaved f4
// chunks {q, q+4, q+8, q+12} of the k-axis, with the matching 4x(4 wires)
// W sub-slices held in 64 VGPRs. All cross-lane traffic (quad butterfly
// reduce + act gather) is DPP quad_perm = pure VALU, zero LDS/DS usage.
// Tail: lane q computes quantum gate q (f,i,g,o) -> no lane waste.

template<int CTRL>
__device__ __forceinline__ float dpp_f(float v) {
    return __int_as_float(__builtin_amdgcn_update_dpp(
        0, __float_as_int(v), CTRL, 0xF, 0xF, true));
}
#define DPP_XOR1 0xB1  // quad_perm [1,0,3,2]
#define DPP_XOR2 0x4E  // quad_perm [2,3,0,1]
#define DPP_BC1  0x55  // quad_perm [1,1,1,1]
#define DPP_BC2  0xAA  // quad_perm [2,2,2,2]
#define DPP_BC3  0xFF  // quad_perm [3,3,3,3]

__device__ __forceinline__ float rcp_fast(float v) {
    return __builtin_amdgcn_rcpf(v);
}
__device__ __forceinline__ float tanh_fast(float v) {
    // 1 - 2/(e^{2v}+1): correct limits at +/-inf
    return 1.0f - 2.0f * rcp_fast(__expf(2.0f * v) + 1.0f);
}
__device__ __forceinline__ float dot4(float4 a, float4 b) {
    return a.x * b.x + a.y * b.y + a.z * b.z + a.w * b.w;
}

__global__ __launch_bounds__(256) void qlstm_kernel(
    const float* __restrict__ x,    // [B,64]
    const float* __restrict__ hx,   // [B,4]
    const float* __restrict__ cx,   // [B,4]
    const float* __restrict__ W,    // [4,68]
    const float* __restrict__ b,    // [4]
    const float* __restrict__ th_f, const float* __restrict__ th_i,
    const float* __restrict__ th_g, const float* __restrict__ th_o,
    float* __restrict__ out_h,      // [B,4]
    float* __restrict__ out_c,      // [B,4]
    int nB)
{
    const int t    = threadIdx.x;
    const int lane = t & 63;
    const int q    = lane & 3;     // k-slot within quad == gate id in tail
    const int r    = lane >> 2;    // row within 16-row group
    const int wv   = t >> 6;       // wave id

    // ---- one-time: per-thread W slice (chunks q,q+4,q+8,q+12; 4 wires) ----
    float4 Wr[4][4];  // [chunk j][wire]
#pragma unroll
    for (int j = 0; j < 4; ++j) {
        const int c = q + 4 * j;   // f4-chunk index along k
#pragma unroll
        for (int wi = 0; wi < 4; ++wi)
            Wr[j][wi] = *(const float4*)(W + wi * 68 + 4 * c);
    }
    const float4 Whv = make_float4(W[0 * 68 + 64 + q], W[1 * 68 + 64 + q],
                                   W[2 * 68 + 64 + q], W[3 * 68 + 64 + q]);
    const float* thp = (q == 0) ? th_f : (q == 1) ? th_i : (q == 2) ? th_g : th_o;
    const float bt0 = b[0] + thp[0], bt1 = b[1] + thp[1];
    const float bt2 = b[2] + thp[2], bt3 = b[3] + thp[3];
    const float Kc = (q == 2) ? 2.0f : 1.0f;   // gate 2 (g) is tanh, else sigmoid

    const int base0 = blockIdx.x * 256 + wv * 64;

#pragma unroll 2
    for (int i = 0; i < 4; ++i) {
        const int row   = base0 + i * 16 + r;
        const bool valid = (row < nB);

        // ---- x read: inst j touches 16 cache lines, 4 lanes merged each ----
        float4 x0 = make_float4(0.f, 0.f, 0.f, 0.f), x1 = x0, x2 = x0, x3 = x0;
        float hv = 0.f;
        if (valid) {
            const float* xp = x + (size_t)row * 64 + 4 * q;
            x0 = *(const float4*)(xp);        // chunk q
            x1 = *(const float4*)(xp + 16);   // chunk q+4
            x2 = *(const float4*)(xp + 32);   // chunk q+8
            x3 = *(const float4*)(xp + 48);   // chunk q+12
            hv = hx[(size_t)row * 4 + q];     // lane-contiguous across wave
        }

        // ---- partial gate_vec (4 wires) over this lane's k-slice ----
        float G0 = hv * Whv.x + dot4(x0, Wr[0][0]) + dot4(x1, Wr[1][0])
                 + dot4(x2, Wr[2][0]) + dot4(x3, Wr[3][0]);
        float G1 = hv * Whv.y + dot4(x0, Wr[0][1]) + dot4(x1, Wr[1][1])
                 + dot4(x2, Wr[2][1]) + dot4(x3, Wr[3][1]);
        float G2 = hv * Whv.z + dot4(x0, Wr[0][2]) + dot4(x1, Wr[1][2])
                 + dot4(x2, Wr[2][2]) + dot4(x3, Wr[3][2]);
        float G3 = hv * Whv.w + dot4(x0, Wr[0][3]) + dot4(x1, Wr[1][3])
                 + dot4(x2, Wr[2][3]) + dot4(x3, Wr[3][3]);

        // ---- quad butterfly: all 4 lanes get full wire sums (pure VALU) ----
        G0 += dpp_f<DPP_XOR1>(G0); G1 += dpp_f<DPP_XOR1>(G1);
        G2 += dpp_f<DPP_XOR1>(G2); G3 += dpp_f<DPP_XOR1>(G3);
        G0 += dpp_f<DPP_XOR2>(G0); G1 += dpp_f<DPP_XOR2>(G1);
        G2 += dpp_f<DPP_XOR2>(G2); G3 += dpp_f<DPP_XOR2>(G3);

        // ---- lane q computes gate q: cos, prefix products, activation ----
        const float z0 = __cosf(G0 + bt0);
        const float z1 = __cosf(G1 + bt1);
        const float z2 = __cosf(G2 + bt2);
        const float z3 = __cosf(G3 + bt3);
        const float z12 = z1 * z2;
        const float e0 = z12 * z3;
        const float e1 = z0 * z1;
        const float e2 = z0 * z12;
        const float e3 = e2 * z3;
        // act = 1 - K/(exp(K*e)+1): K=1 -> sigmoid, K=2 -> tanh
        const float a0 = 1.0f - Kc * rcp_fast(__expf(Kc * e0) + 1.0f);
        const float a1 = 1.0f - Kc * rcp_fast(__expf(Kc * e1) + 1.0f);
        const float a2 = 1.0f - Kc * rcp_fast(__expf(Kc * e2) + 1.0f);
        const float a3 = 1.0f - Kc * rcp_fast(__expf(Kc * e3) + 1.0f);

        // ---- gather i,g,o to quad lane 0 (lane 0's own a* = f) ----
        const float i0 = dpp_f<DPP_BC1>(a0), i1 = dpp_f<DPP_BC1>(a1);
        const float i2 = dpp_f<DPP_BC1>(a2), i3 = dpp_f<DPP_BC1>(a3);
        const float g0 = dpp_f<DPP_BC2>(a0), g1 = dpp_f<DPP_BC2>(a1);
        const float g2 = dpp_f<DPP_BC2>(a2), g3 = dpp_f<DPP_BC2>(a3);
        const float o0 = dpp_f<DPP_BC3>(a0), o1 = dpp_f<DPP_BC3>(a1);
        const float o2 = dpp_f<DPP_BC3>(a2), o3 = dpp_f<DPP_BC3>(a3);

        if (q == 0 && valid) {
            const float4 c = *(const float4*)(cx + (size_t)row * 4);
            const float cn0 = a0 * c.x + i0 * g0;
            const float cn1 = a1 * c.y + i1 * g1;
            const float cn2 = a2 * c.z + i2 * g2;
            const float cn3 = a3 * c.w + i3 * g3;
            const float hn0 = o0 * tanh_fast(cn0);
            const float hn1 = o1 * tanh_fast(cn1);
            const float hn2 = o2 * tanh_fast(cn2);
            const float hn3 = o3 * tanh_fast(cn3);
            *(float4*)(out_c + (size_t)row * 4) = make_float4(cn0, cn1, cn2, cn3);
            *(float4*)(out_h + (size_t)row * 4) = make_float4(hn0, hn1, hn2, hn3);
        }
    }
}

extern "C" void kernel_launch(void* const* d_in, const int* in_sizes, int n_in,
                              void* d_out, int out_size, void* d_ws, size_t ws_size,
                              hipStream_t stream) {
    const float* x    = (const float*)d_in[0];
    const float* hx   = (const float*)d_in[1];
    const float* cx   = (const float*)d_in[2];
    const float* W    = (const float*)d_in[3];
    const float* b    = (const float*)d_in[4];
    const float* th_f = (const float*)d_in[5];
    const float* th_i = (const float*)d_in[6];
    const float* th_g = (const float*)d_in[7];
    const float* th_o = (const float*)d_in[8];

    const int nB = in_sizes[0] / 64;          // 524288
    float* out_h = (float*)d_out;             // [B,4]
    float* out_c = out_h + (size_t)nB * 4;    // [B,4]

    const int blocks = (nB + 255) / 256;      // 2048 (256 rows per block)
    hipLaunchKernelGGL(qlstm_kernel, dim3(blocks), dim3(256), 0, stream,
                       x, hx, cx, W, b, th_f, th_i, th_g, th_o, out_h, out_c, nB);
}